// Round 6
// baseline (48.217 us; speedup 1.0000x reference)
//
#include <hip/hip_runtime.h>
#include <hip/hip_bf16.h>

// ws layout (requires ws_size >= 17039360 B):
//   [0, 221184)        : weights as bf16 in MFMA B-fragment order
//   [221184, 221440)   : 256 B of zeros (OOB halo source)
//   [262144, 17039360) : x_t = x transposed to [b][s][c] bf16 (16 MiB)
#define WS_W_OFF    0
#define WS_ZERO_OFF 221184
#define WS_XT_OFF   262144

typedef __attribute__((ext_vector_type(8))) short s16x8;
typedef __attribute__((ext_vector_type(4))) float f32x4;

#define GLOBAL_AS __attribute__((address_space(1)))
#define LDS_AS    __attribute__((address_space(3)))

__device__ __forceinline__ unsigned short f2bf(float f) {
  // round-to-nearest-even bf16 (inputs are normal randoms; no NaN handling needed)
  unsigned u = __builtin_bit_cast(unsigned, f);
  u = u + 0x7fffu + ((u >> 16) & 1u);
  return (unsigned short)(u >> 16);
}

// ---------------------------------------------------------------------------
// Fused prep: blocks [0,432) repack weights; blocks [432,4528) transpose x.
//
// Weights: W[cout][cin][tap] fp32 -> bf16 fragments.
// Fragment f = (tap*2+h)*4+nf holds B[n][k] for n = nf*16 + (lane&15),
// cin = h*32 + (lane>>4)*8 + j  (16x16x32 MFMA B layout, contiguous-k per lane).
// bf16 index = (f*64 + lane)*8 + j. The 4 KB tile for (tap,h) is contiguous
// at byte offset (tap*2+h)*4096.
//
// x: NCDHW fp32 -> x_t[b][s][c] bf16 (channels-last). Reads coalesced along s.
__global__ void prep_kernel(const float* __restrict__ x,
                            const float* __restrict__ w,
                            unsigned short* __restrict__ wsw,
                            float* __restrict__ zeros,
                            unsigned short* __restrict__ xt) {
  int blk = blockIdx.x;
  if (blk < 432) {
    int t = blk * 256 + threadIdx.x;             // 110592 threads exactly
    int tap  = t % 27;
    int cin  = (t / 27) & 63;
    int cout = t / (27 * 64);
    int h   = cin >> 5;
    int q   = (cin >> 3) & 3;
    int j   = cin & 7;
    int nf  = cout >> 4;
    int lane = q * 16 + (cout & 15);
    int dst = (((tap * 2 + h) * 4 + nf) * 64 + lane) * 8 + j;
    wsw[dst] = f2bf(w[t]);
    if (t < 64) zeros[t] = 0.0f;
  } else {
    int t  = (blk - 432) * 256 + threadIdx.x;    // 1048576 threads
    int s  = t & 32767;
    int c8 = (t >> 15) & 7;
    int b  = t >> 18;
    const float* src = x + (size_t)(b * 64 + c8 * 8) * 32768 + s;
    s16x8 v;
    #pragma unroll
    for (int k = 0; k < 8; ++k) v[k] = (short)f2bf(src[(size_t)k * 32768]);
    *(s16x8*)(xt + (size_t)(b * 32768 + s) * 64 + c8 * 8) = v;
  }
}

// ---------------------------------------------------------------------------
// Implicit-GEMM conv. Block = (b, z-pair, y-quad): 2z x 4y x 32x = 256 outputs
// x 64 couts, 256 threads = 4 waves. Wave w owns z = z0+(w>>1), y-rows
// {y0+2(w&1), +1}: M_w = 64.
//
// B pipeline is STRUCTURAL (2-phase, T3-lite): each tap's 4 KB B-tile is
// staged global->LDS (1x16B per thread) one tap ahead into a double buffer;
// the per-tap __syncthreads (vmcnt(0)+lgkmcnt(0) drain) guarantees arrival.
// No reliance on compiler load scheduling; B vector-memory traffic drops 4x
// (once per block, not per wave). A halo staged per cin-half as before.
//
// Halo layout LINEAR: position pos at halo[pos*64], cin-chunk c (16 B) at
// +c*16. A-read and B-read are both 64-lane x consecutive-16B patterns:
// 8 dwords/bank, conflict-free.
__global__ __launch_bounds__(256, 2) void conv_kernel(const float* __restrict__ bias,
                                                      float* __restrict__ out,
                                                      const char* __restrict__ ws) {
  __shared__ __align__(16) unsigned char halo[52 * 1024];  // 832 pos (816 used)
  __shared__ __align__(16) unsigned char blds[2][4096];    // B tap double-buffer

  const int tid  = threadIdx.x;
  const int lane = tid & 63;
  const int w    = tid >> 6;                     // wave id 0..3
  // XCD-aware swizzle (512 % 8 == 0 -> bijective): each XCD gets 64 contiguous
  // logical blocks (fixed b, 8 consecutive z-pairs) -> ~2.4 MB x_t slab in L2.
  const int logical = (blockIdx.x & 7) * 64 + (blockIdx.x >> 3);
  const int yt = logical & 7, zt = (logical >> 3) & 15, b = logical >> 7;
  const int z0 = zt * 2, y0 = yt * 4;
  const int zo  = w >> 1;                        // wave z within pair
  const int yo2 = (w & 1) * 2;                   // wave y-pair base

  const int r15 = lane & 15;
  const int hi4 = lane >> 4;

  // halo staging: granule = 1024 B = 16 positions; lane l -> pos g*16 + (l>>2),
  // 16B chunk l&3. All linear (dest and source).
  const int sl_sub   = lane >> 2;
  const int sl_chunk = lane & 3;

  auto stage_halo = [&](int h) {
    for (int g = w; g < 52; g += 4) {            // 13 granules per wave
      int pos = g * 16 + sl_sub;
      int hz = pos / 204; int rem = pos - hz * 204;        // 204 = 6*34
      int hy = rem / 34;  int hx = rem - hy * 34;
      int gz = z0 + hz - 1, gy = y0 + hy - 1, gx = hx - 1;
      bool inb = (pos < 816) & ((unsigned)gz < 32u) &
                 ((unsigned)gy < 32u) & ((unsigned)gx < 32u);
      int s = (gz * 32 + gy) * 32 + gx;
      int src = inb ? (WS_XT_OFF + (b * 32768 + s) * 128 + h * 64 + sl_chunk * 16)
                    : WS_ZERO_OFF;
      __builtin_amdgcn_global_load_lds(
          (const GLOBAL_AS void*)(ws + src),
          (LDS_AS void*)(&halo[g * 1024 + lane * 16]),
          16, 0, 0);
    }
  };

  // B staging: whole block moves one (h,tap) 4 KB tile, 16 B per thread.
  // LDS dest = wave-uniform base (w*1024) + lane*16 (global_load_lds rule).
  auto stage_B = [&](int h, int tap, int pbuf) {
    __builtin_amdgcn_global_load_lds(
        (const GLOBAL_AS void*)(ws + WS_W_OFF + (tap * 2 + h) * 4096 + tid * 16),
        (LDS_AS void*)(&blds[pbuf][tid * 16]),
        16, 0, 0);
  };

  f32x4 zero4 = {0.f, 0.f, 0.f, 0.f};
  f32x4 acc[4][4];
  #pragma unroll
  for (int mf = 0; mf < 4; ++mf)
    #pragma unroll
    for (int nf = 0; nf < 4; ++nf) acc[mf][nf] = zero4;

  s16x8 Br[4], A0[4], A1[4];

  auto loadBregs = [&](s16x8* dst, int pbuf) {
    #pragma unroll
    for (int nf = 0; nf < 4; ++nf)
      dst[nf] = *(const s16x8*)&blds[pbuf][(nf * 64 + lane) * 16];
  };

  // A fragment for tap: mf = (dy = mf>>1, xh = mf&1); lane l reads position
  // base + dy*34 + xh*16 + (l&15), cin-chunk l>>4 (k = (l>>4)*8 + j).
  auto loadA = [&](s16x8* a, int tap) {
    int kd = tap / 9; int r9 = tap - kd * 9;
    int kh = r9 / 3;  int kw = r9 - kh * 3;
    int base = ((zo + kd) * 6 + (yo2 + kh)) * 34 + kw + r15;
    #pragma unroll
    for (int mf = 0; mf < 4; ++mf) {
      int pos = base + (mf >> 1) * 34 + (mf & 1) * 16;
      a[mf] = *(const s16x8*)&halo[pos * 64 + hi4 * 16];
    }
  };

  auto compute = [&](const s16x8* a, const s16x8* B) {
    #pragma unroll
    for (int mf = 0; mf < 4; ++mf)
      #pragma unroll
      for (int nf = 0; nf < 4; ++nf)
        acc[mf][nf] = __builtin_amdgcn_mfma_f32_16x16x32_bf16(
            a[mf], B[nf], acc[mf][nf], 0, 0, 0);
  };

  #pragma unroll 1
  for (int h = 0; h < 2; ++h) {
    if (h) __syncthreads();        // all waves done with half-0 tap-26 reads
    stage_halo(h);
    stage_B(h, 0, 0);
    __syncthreads();               // drains halo + B(h,0); orders LDS for block

    loadA(A0, 0);
    #pragma unroll 1
    for (int tt = 0; tt < 13; ++tt) {            // taps 2tt, 2tt+1
      // tap 2tt: B in blds[0]
      loadBregs(Br, 0);
      stage_B(h, 2 * tt + 1, 1);
      loadA(A1, 2 * tt + 1);
      compute(A0, Br);
      __syncthreads();             // drains stage_B(2tt+1); blds[1] ready
      // tap 2tt+1: B in blds[1]
      loadBregs(Br, 1);
      stage_B(h, 2 * tt + 2, 0);   // tap <= 26
      loadA(A0, 2 * tt + 2);
      compute(A1, Br);
      __syncthreads();             // drains stage_B(2tt+2); blds[0] ready
    }
    // tap 26: B in blds[0], A in A0
    loadBregs(Br, 0);
    compute(A0, Br);
  }

  // ---- epilogue: D row = x (within 16-frag), col = cout (round-1 verified) ----
  const int z = z0 + zo;
  #pragma unroll
  for (int nf = 0; nf < 4; ++nf) {
    int cout = nf * 16 + r15;
    float bv = bias[cout];
    #pragma unroll
    for (int mf = 0; mf < 4; ++mf) {
      int y  = y0 + yo2 + (mf >> 1);
      int x0 = (mf & 1) * 16 + 4 * hi4;
      float* orow = out + ((size_t)((b * 64 + cout) * 32 + z) * 32 + y) * 32;
      f32x4 v;
      #pragma unroll
      for (int r = 0; r < 4; ++r) v[r] = acc[mf][nf][r] + bv;
      *(f32x4*)&orow[x0] = v;
    }
  }
}

extern "C" void kernel_launch(void* const* d_in, const int* in_sizes, int n_in,
                              void* d_out, int out_size, void* d_ws, size_t ws_size,
                              hipStream_t stream) {
  const float* x    = (const float*)d_in[0];
  const float* wgt  = (const float*)d_in[1];
  const float* bias = (const float*)d_in[2];
  float* out = (float*)d_out;
  char* ws = (char*)d_ws;

  prep_kernel<<<4528, 256, 0, stream>>>(x, wgt,
                                        (unsigned short*)(ws + WS_W_OFF),
                                        (float*)(ws + WS_ZERO_OFF),
                                        (unsigned short*)(ws + WS_XT_OFF));
  conv_kernel<<<512, 256, 0, stream>>>(bias, out, ws);
}